// Round 9
// baseline (252.601 us; speedup 1.0000x reference)
//
#include <hip/hip_runtime.h>

// CoFormer attention layer, MI355X gfx950.
// B=4, S=2048, D=512, H=8, dh=64, K=30, NVAR=8. valid_mask all-true ->
// layer1: attend iff same variate (dense per-group attention, MFMA flash).
// layer2: attend iff in 30-NN by |dt| among different variates.
// KNN: tau = exact 30th-smallest key via bit-pattern binary search; set =
// {d < tau} U {first (30-cntLess) idx with d == tau} == jax top_k set.
//
// R8 -> R9: gemm_bt staging switched to global_load_lds width=16 (async
// DMA to LDS; linear dest per HW constraint) with row&3 XOR slot swizzle
// applied to BOTH global source and fragment read (4-way max conflicts).

#define S_LEN 2048
#define BATCH 4
#define DM    512
#define NH    8
#define DH    64
#define KNN_K 30
#define NVAR  8
#define NTOK  (BATCH * S_LEN)   // 8192
#define QKVD  (3 * DM)          // 1536
#define PADCAP 2560             // 2048 + 8*64 padding headroom per batch
#define MAXTILE 40              // max q-tiles (64 rows) per batch

typedef float f32x4 __attribute__((ext_vector_type(4)));
typedef short s16x8 __attribute__((ext_vector_type(8)));
typedef short s16x4 __attribute__((ext_vector_type(4)));

__device__ __forceinline__ float bf2f(short u) {
  return __uint_as_float(((unsigned)(unsigned short)u) << 16);
}
__device__ __forceinline__ short f2bf(float f) {
  unsigned x = __float_as_uint(f);
  return (short)((x + 0x7fffu + ((x >> 16) & 1u)) >> 16);   // RNE
}

__device__ __forceinline__ void gload16(const void* g, void* l) {
  __builtin_amdgcn_global_load_lds(
      (const __attribute__((address_space(1))) unsigned*)g,
      (__attribute__((address_space(3))) unsigned*)l, 16, 0, 0);
}

// ---------------- fused cast f32 -> bf16 over 5 buffers ----------------
#define C_N0 (NTOK * DM / 4)          // x       1048576
#define C_N1 (QKVD * DM / 4)          // in_w1    196608
#define C_N2 (DM * DM / 4)            // out_w1    65536
#define C_B1 (C_N0 + C_N1)
#define C_B2 (C_B1 + C_N2)
#define C_B3 (C_B2 + C_N1)
#define C_B4 (C_B3 + C_N2)            // total 1572864 -> 6144 blocks
__global__ __launch_bounds__(256) void cast_all(
    const float* __restrict__ s0, const float* __restrict__ s1,
    const float* __restrict__ s2, const float* __restrict__ s3,
    const float* __restrict__ s4, short* __restrict__ d0,
    short* __restrict__ d1, short* __restrict__ d2,
    short* __restrict__ d3, short* __restrict__ d4) {
  int i = blockIdx.x * 256 + threadIdx.x;
  const float* src; short* dst; int k;
  if (i < C_N0)      { src = s0; dst = d0; k = i; }
  else if (i < C_B1) { src = s1; dst = d1; k = i - C_N0; }
  else if (i < C_B2) { src = s2; dst = d2; k = i - C_B1; }
  else if (i < C_B3) { src = s3; dst = d3; k = i - C_B2; }
  else               { src = s4; dst = d4; k = i - C_B3; }
  float4 v = ((const float4*)src)[k];
  s16x4 o;
  o[0] = f2bf(v.x); o[1] = f2bf(v.y); o[2] = f2bf(v.z); o[3] = f2bf(v.w);
  ((s16x4*)dst)[k] = o;
}

// ---------------- group tables: parallel slice-count + prefix + scatter ----------------
__global__ void build_groups(const int* __restrict__ variates,
                             int* __restrict__ gcnt, int* __restrict__ pgoff,
                             int* __restrict__ porig, int* __restrict__ tileV,
                             int* __restrict__ tileQ0, int* __restrict__ ntile) {
  int b = blockIdx.x, t = threadIdx.x;   // 64 threads, 1 wave
  __shared__ int scnt[64][NVAR];
  __shared__ int soff[64][NVAR];
  __shared__ int stot[NVAR], sbase[NVAR];
  for (int p = t; p < PADCAP; p += 64) porig[b * PADCAP + p] = -1;
  const int* vb = variates + b * S_LEN;
  int c[NVAR] = {0, 0, 0, 0, 0, 0, 0, 0};
  for (int j = t * 32; j < t * 32 + 32; ++j) {
    int v = vb[j];
#pragma unroll
    for (int u = 0; u < NVAR; ++u) c[u] += (v == u);
  }
#pragma unroll
  for (int u = 0; u < NVAR; ++u) scnt[t][u] = c[u];
  __syncthreads();
  if (t < NVAR) {
    int a = 0;
    for (int u = 0; u < 64; ++u) { soff[u][t] = a; a += scnt[u][t]; }
    stot[t] = a;
  }
  __syncthreads();
  if (t == 0) {
    int a = 0, nt = 0;
    for (int v = 0; v < NVAR; ++v) {
      sbase[v] = a;
      pgoff[b * NVAR + v] = a;
      gcnt[b * NVAR + v] = stot[v];
      int ntv = (stot[v] + 63) >> 6;
      for (int i = 0; i < ntv; ++i) {
        tileV[b * MAXTILE + nt] = v;
        tileQ0[b * MAXTILE + nt] = a + i * 64;
        ++nt;
      }
      a += ntv * 64;
    }
    ntile[b] = nt;
  }
  __syncthreads();
  int o[NVAR];
#pragma unroll
  for (int u = 0; u < NVAR; ++u) o[u] = sbase[u] + soff[t][u];
  for (int j = t * 32; j < t * 32 + 32; ++j) {
    int v = vb[j];
    int dst = 0;
#pragma unroll
    for (int u = 0; u < NVAR; ++u) dst += (v == u) ? o[u] : 0;
    porig[b * PADCAP + dst] = j;
#pragma unroll
    for (int u = 0; u < NVAR; ++u) o[u] += (v == u);
  }
}

// ---------------- KNN-30: dual-query wave, binary search on float bits ----------------
__global__ __launch_bounds__(256) void knn_sel(const int* __restrict__ variates,
                                               const float* __restrict__ times,
                                               int* __restrict__ out) {
  int w = threadIdx.x >> 6, lane = threadIdx.x & 63;
  int bq0 = blockIdx.x * 8 + w * 2;
  int bq1 = bq0 + 1;
  int b = bq0 >> 11;
  float tq0 = times[bq0], tq1 = times[bq1];
  int vq0 = variates[bq0], vq1 = variates[bq1];
  const float* tb = times + b * S_LEN;
  const int* vb = variates + b * S_LEN;
  int j0 = lane * 32;

  unsigned u0[32], u1[32];
#pragma unroll
  for (int q = 0; q < 8; ++q) {
    float4 t4 = *(const float4*)(tb + j0 + q * 4);
    int4 v4 = *(const int4*)(vb + j0 + q * 4);
    u0[q * 4 + 0] = __float_as_uint((v4.x == vq0) ? __builtin_inff() : fabsf(tq0 - t4.x));
    u0[q * 4 + 1] = __float_as_uint((v4.y == vq0) ? __builtin_inff() : fabsf(tq0 - t4.y));
    u0[q * 4 + 2] = __float_as_uint((v4.z == vq0) ? __builtin_inff() : fabsf(tq0 - t4.z));
    u0[q * 4 + 3] = __float_as_uint((v4.w == vq0) ? __builtin_inff() : fabsf(tq0 - t4.w));
    u1[q * 4 + 0] = __float_as_uint((v4.x == vq1) ? __builtin_inff() : fabsf(tq1 - t4.x));
    u1[q * 4 + 1] = __float_as_uint((v4.y == vq1) ? __builtin_inff() : fabsf(tq1 - t4.y));
    u1[q * 4 + 2] = __float_as_uint((v4.z == vq1) ? __builtin_inff() : fabsf(tq1 - t4.z));
    u1[q * 4 + 3] = __float_as_uint((v4.w == vq1) ? __builtin_inff() : fabsf(tq1 - t4.w));
  }

  unsigned lo0 = 0u, hi0 = 0x7F800000u;
  unsigned lo1 = 0u, hi1 = 0x7F800000u;
  for (int it = 0; it < 31; ++it) {
    unsigned mid0 = lo0 + ((hi0 - lo0) >> 1);
    unsigned mid1 = lo1 + ((hi1 - lo1) >> 1);
    int c0 = 0, c1 = 0;
#pragma unroll
    for (int k = 0; k < 32; ++k) {
      c0 += (u0[k] <= mid0) ? 1 : 0;
      c1 += (u1[k] <= mid1) ? 1 : 0;
    }
    int pc = c0 | (c1 << 16);          // both counts <= 2048: no carry
#pragma unroll
    for (int o2 = 32; o2; o2 >>= 1) pc += __shfl_xor(pc, o2);
    int pc0 = pc & 0xffff, pc1 = pc >> 16;
    if (lo0 < hi0) { if (pc0 >= KNN_K) hi0 = mid0; else lo0 = mid0 + 1; }
    if (lo1 < hi1) { if (pc1 >= KNN_K) hi1 = mid1; else lo1 = mid1 + 1; }
  }
  unsigned tau0 = lo0, tau1 = lo1;

  int cl0 = 0, ce0 = 0, cl1 = 0, ce1 = 0;
#pragma unroll
  for (int k = 0; k < 32; ++k) {
    cl0 += (u0[k] < tau0) ? 1 : 0;  ce0 += (u0[k] == tau0) ? 1 : 0;
    cl1 += (u1[k] < tau1) ? 1 : 0;  ce1 += (u1[k] == tau1) ? 1 : 0;
  }
  int pa = cl0 | (cl1 << 16), pe = ce0 | (ce1 << 16);
#pragma unroll
  for (int o2 = 1; o2 < 64; o2 <<= 1) {
    int ta = __shfl_up(pa, o2);
    int te = __shfl_up(pe, o2);
    if (lane >= o2) { pa += ta; pe += te; }
  }
  int paTop = __shfl(pa, 63);
  int totL0 = paTop & 0xffff, totL1 = paTop >> 16;
  int excl0 = (pa & 0xffff) - cl0, excl1 = (pa >> 16) - cl1;
  int exce0 = totL0 + (pe & 0xffff) - ce0, exce1 = totL1 + (pe >> 16) - ce1;

  int* op0 = out + bq0 * KNN_K;
  int* op1 = out + bq1 * KNN_K;
  int pos0 = excl0, pos1 = excl1;
#pragma unroll
  for (int k = 0; k < 32; ++k) {
    if (u0[k] < tau0) { op0[pos0] = j0 + k; ++pos0; }
    if (u1[k] < tau1) { op1[pos1] = j0 + k; ++pos1; }
  }
  int r0 = exce0, r1 = exce1;
#pragma unroll
  for (int k = 0; k < 32; ++k) {
    if (u0[k] == tau0) { if (r0 < KNN_K) op0[r0] = j0 + k; ++r0; }
    if (u1[k] == tau1) { if (r1 < KNN_K) op1[r1] = j0 + k; ++r1; }
  }
}

// ---------------- bf16 MFMA GEMM: C[M,N] = A[M,K] @ B[N,K]^T (+bias) ----------------
// 128x128 tile, BK=32, global_load_lds width=16 staging (linear LDS dest),
// row&3 XOR slot swizzle on source + fragment read (4-way max conflicts).
template <int OUT_BF16>
__global__ __launch_bounds__(256) void gemm_bt(const short* __restrict__ A,
                                               const short* __restrict__ Bm,
                                               const float* __restrict__ bias,
                                               void* __restrict__ Cout,
                                               int M, int N, int K) {
  __shared__ short sA[128 * 32];   // 64B rows, linear (gload dest)
  __shared__ short sB[128 * 32];
  int n0 = blockIdx.x * 128, m0 = blockIdx.y * 128;
  int tid = threadIdx.x;
  int lane = tid & 63, wv = tid >> 6;
  int wr = wv >> 1, wc = wv & 1;

  // staging geometry: wave wv covers rows [wv*32, wv*32+32), 2 instrs x 16 rows
  int srow = lane >> 2;            // row within 16-row instr
  int sslot = lane & 3;            // 16B slot within 64B row (linear LDS dest)

  f32x4 acc[4][4] = {};
  int nk = K >> 5;

  for (int kt = 0; kt < nk; ++kt) {
    __syncthreads();               // all waves done reading prev-step LDS
#pragma unroll
    for (int i = 0; i < 2; ++i) {
      int row = wv * 32 + i * 16 + srow;
      int g = sslot ^ (row & 3);   // pre-swizzled source slot (involution)
      const short* ga = A + (size_t)(m0 + row) * K + kt * 32 + g * 8;
      const short* gb = Bm + (size_t)(n0 + row) * K + kt * 32 + g * 8;
      char* la = (char*)sA + (wv * 32 + i * 16) * 64;   // wave-uniform base
      char* lb = (char*)sB + (wv * 32 + i * 16) * 64;
      gload16(ga, la);
      gload16(gb, lb);
    }
    __syncthreads();               // compiler drains vmcnt(0) before barrier

    int kg = lane >> 4;            // k-group (16B of 8 bf16)
    int ar = wr * 64 + (lane & 15);
    int br = wc * 64 + (lane & 15);
    s16x8 af[4], bf[4];
#pragma unroll
    for (int m = 0; m < 4; ++m) {
      int row = ar + m * 16;
      af[m] = *(const s16x8*)((char*)sA + row * 64 + (kg ^ (row & 3)) * 16);
    }
#pragma unroll
    for (int n = 0; n < 4; ++n) {
      int row = br + n * 16;
      bf[n] = *(const s16x8*)((char*)sB + row * 64 + (kg ^ (row & 3)) * 16);
    }
#pragma unroll
    for (int m = 0; m < 4; ++m)
#pragma unroll
      for (int n = 0; n < 4; ++n)
        acc[m][n] = __builtin_amdgcn_mfma_f32_16x16x32_bf16(af[m], bf[n], acc[m][n], 0, 0, 0);
  }

  int crow0 = m0 + wr * 64 + ((lane >> 4) * 4);
  int ccol0 = n0 + wc * 64 + (lane & 15);
#pragma unroll
  for (int n = 0; n < 4; ++n) {
    int col = ccol0 + n * 16;
    float bv = bias ? bias[col] : 0.f;
#pragma unroll
    for (int m = 0; m < 4; ++m) {
#pragma unroll
      for (int j = 0; j < 4; ++j) {
        int row = crow0 + m * 16 + j;
        float val = acc[m][n][j] + bv;
        if (OUT_BF16)
          ((short*)Cout)[(size_t)row * N + col] = f2bf(val);
        else
          ((float*)Cout)[(size_t)row * N + col] = val;
      }
    }
  }
}

// ---------------- permute QKV to group-padded order; zero pads; pre-scale Q ----------------
__global__ __launch_bounds__(192) void permute_qkv(const short* __restrict__ qkvb,
                                                   const int* __restrict__ porig,
                                                   short* __restrict__ pq) {
  int row = blockIdx.x;              // b*PADCAP + p
  int b = row / PADCAP;
  int orig = porig[row];
  int t = threadIdx.x;               // 0..191, 8 shorts each
  s16x8 val;
  if (orig >= 0) {
    val = *(const s16x8*)(qkvb + ((size_t)(b * S_LEN + orig)) * QKVD + t * 8);
    if (t < 64) {                    // Q slice: pre-scale by 1/8 (exact)
#pragma unroll
      for (int i = 0; i < 8; ++i) val[i] = f2bf(bf2f(val[i]) * 0.125f);
    }
  } else {
#pragma unroll
    for (int i = 0; i < 8; ++i) val[i] = 0;
  }
  *(s16x8*)(pq + (size_t)row * QKVD + t * 8) = val;
}

// ---------------- intra attention: dense per-group MFMA flash ----------------
__global__ __launch_bounds__(256) void intra_attn(
    const short* __restrict__ pq, const int* __restrict__ porig,
    const int* __restrict__ tileV, const int* __restrict__ tileQ0,
    const int* __restrict__ ntile, const int* __restrict__ pgoff,
    const int* __restrict__ gcnt, short* __restrict__ o) {
  int b = blockIdx.z, h = blockIdx.y, t = blockIdx.x;
  if (t >= ntile[b]) return;
  int v = tileV[b * MAXTILE + t];
  int q0 = tileQ0[b * MAXTILE + t];
  int k0 = pgoff[b * NVAR + v];
  int L = gcnt[b * NVAR + v];
  int nch = (L + 63) >> 6;

  __shared__ short sQ[2][64][40];
  __shared__ short sK[2][64][40];
  __shared__ short sVT[2][64][40];
  __shared__ short sP[2][64][40];

  int tid = threadIdx.x, lane = tid & 63, w = tid >> 6;
  int colbase = lane & 15;
  int kfrag = (lane >> 4) * 8;

  {
    int r = tid >> 2, cc = (tid & 3) * 16;
    const short* src = pq + ((size_t)(b * PADCAP + q0 + r)) * QKVD + h * DH + cc;
    s16x8 v0 = *(const s16x8*)src;
    s16x8 v1 = *(const s16x8*)(src + 8);
    int half = cc >> 5, kk = cc & 31;
    *(s16x8*)&sQ[half][r][kk] = v0;
    *(s16x8*)&sQ[half][r][kk + 8] = v1;
  }

  f32x4 accO[4] = {};
  float mrun[4], lrun[4];
#pragma unroll
  for (int j = 0; j < 4; ++j) { mrun[j] = -__builtin_inff(); lrun[j] = 0.f; }

  for (int c = 0; c < nch; ++c) {
    __syncthreads();
    {
      int r = tid >> 2, cc = (tid & 3) * 16;
      size_t rowg = (size_t)(b * PADCAP + k0 + c * 64 + r) * QKVD;
      const short* srcK = pq + rowg + DM + h * DH + cc;
      s16x8 k0v = *(const s16x8*)srcK;
      s16x8 k1v = *(const s16x8*)(srcK + 8);
      int half = cc >> 5, kk = cc & 31;
      *(s16x8*)&sK[half][r][kk] = k0v;
      *(s16x8*)&sK[half][r][kk + 8] = k1v;
      const short* srcV = pq + rowg + 2 * DM + h * DH + cc;
      s16x8 v0v = *(const s16x8*)srcV;
      s16x8 v1v = *(const s16x8*)(srcV + 8);
      int khalf = r >> 5, kkv = r & 31;
#pragma unroll
      for (int i = 0; i < 8; ++i) sVT[khalf][cc + i][kkv] = v0v[i];
#pragma unroll
      for (int i = 0; i < 8; ++i) sVT[khalf][cc + 8 + i][kkv] = v1v[i];
    }
    __syncthreads();

    s16x8 aQ0 = *(const s16x8*)&sQ[0][w * 16 + colbase][kfrag];
    s16x8 aQ1 = *(const s16x8*)&sQ[1][w * 16 + colbase][kfrag];
    f32x4 accS[4] = {};
#pragma unroll
    for (int n = 0; n < 4; ++n) {
      s16x8 b0 = *(const s16x8*)&sK[0][n * 16 + colbase][kfrag];
      s16x8 b1 = *(const s16x8*)&sK[1][n * 16 + colbase][kfrag];
      accS[n] = __builtin_amdgcn_mfma_f32_16x16x32_bf16(aQ0, b0, accS[n], 0, 0, 0);
      accS[n] = __builtin_amdgcn_mfma_f32_16x16x32_bf16(aQ1, b1, accS[n], 0, 0, 0);
    }

    float pv[4][4];
#pragma unroll
    for (int j = 0; j < 4; ++j) {
      float cm = -__builtin_inff();
#pragma unroll
      for (int n = 0; n < 4; ++n) {
        bool ok = (c * 64 + n * 16 + colbase) < L;
        float se = ok ? accS[n][j] : -__builtin_inff();
        cm = fmaxf(cm, se);
      }
      for (int o2 = 8; o2; o2 >>= 1) cm = fmaxf(cm, __shfl_xor(cm, o2));
      float mn = fmaxf(mrun[j], cm);
      float al = __expf(mrun[j] - mn);
      float rs = 0.f;
#pragma unroll
      for (int n = 0; n < 4; ++n) {
        bool ok = (c * 64 + n * 16 + colbase) < L;
        float p = ok ? __expf(accS[n][j] - mn) : 0.f;
        pv[n][j] = p;
        rs += p;
      }
      for (int o2 = 8; o2; o2 >>= 1) rs += __shfl_xor(rs, o2);
      lrun[j] = lrun[j] * al + rs;
      mrun[j] = mn;
#pragma unroll
      for (int n = 0; n < 4; ++n) accO[n][j] *= al;
    }

    int prow = w * 16 + ((lane >> 4) << 2);
#pragma unroll
    for (int n = 0; n < 4; ++n)
#pragma unroll
      for (int j = 0; j < 4; ++j)
        sP[n >> 1][prow + j][colbase + ((n & 1) << 4)] = f2bf(pv[n][j]);

    s16x8 aP0 = *(const s16x8*)&sP[0][w * 16 + colbase][kfrag];
    s16x8 aP1 = *(const s16x8*)&sP[1][w * 16 + colbase][kfrag];
#pragma unroll
    for (int n = 0; n < 4; ++n) {
      s16x8 b0 = *(const s16x8*)&sVT[0][n * 16 + colbase][kfrag];
      s16x8 b1 = *(const s16x8*)&sVT[1][n * 16 + colbase][kfrag];
      accO[n] = __builtin_amdgcn_mfma_f32_16x16x32_bf16(aP0, b0, accO[n], 0, 0, 0);
      accO[n] = __builtin_amdgcn_mfma_f32_16x16x32_bf16(aP1, b1, accO[n], 0, 0, 0);
    }
  }

#pragma unroll
  for (int j = 0; j < 4; ++j) {
    int prow = w * 16 + (lane >> 4) * 4 + j;
    int orig = porig[b * PADCAP + q0 + prow];
    if (orig >= 0) {
      float inv = 1.f / lrun[j];
      size_t base = ((size_t)(b * S_LEN + orig)) * DM + h * DH;
#pragma unroll
      for (int n = 0; n < 4; ++n)
        o[base + n * 16 + colbase] = f2bf(accO[n][j] * inv);
    }
  }
}

// ---------------- inter (KNN) attention: one wave per query, all 8 heads ----------------
__global__ __launch_bounds__(256) void inter_attn(const short* __restrict__ qkv,
                                                  const int* __restrict__ knn,
                                                  short* __restrict__ o) {
  __shared__ float sS[4][NH][32];
  __shared__ float sP[4][NH][32];
  int tid = threadIdx.x, lane = tid & 63, w = tid >> 6;
  int bq = blockIdx.x * 4 + w;
  int b = bq >> 11;
  int h = lane >> 3;

  int myidx = (lane < KNN_K) ? knn[bq * KNN_K + lane] : 0;

  s16x8 q8 = *(const s16x8*)(qkv + (size_t)bq * QKVD + lane * 8);
  float qf[8];
#pragma unroll
  for (int i = 0; i < 8; ++i) qf[i] = bf2f(q8[i]) * 0.125f;

  for (int j = 0; j < KNN_K; ++j) {
    int idx = __shfl(myidx, j);
    s16x8 k8 = *(const s16x8*)(qkv + ((size_t)(b * S_LEN + idx)) * QKVD + DM + lane * 8);
    float acc = 0.f;
#pragma unroll
    for (int i = 0; i < 8; ++i) acc += qf[i] * bf2f(k8[i]);
    acc += __shfl_xor(acc, 1);
    acc += __shfl_xor(acc, 2);
    acc += __shfl_xor(acc, 4);
    if ((lane & 7) == 0) sS[w][h][j] = acc;
  }

  int jsub = lane & 7;
  float sv0 = sS[w][h][jsub];
  float sv1 = sS[w][h][jsub + 8];
  float sv2 = sS[w][h][jsub + 16];
  float sv3 = (jsub < 6) ? sS[w][h][jsub + 24] : -__builtin_inff();
  float m = fmaxf(fmaxf(sv0, sv1), fmaxf(sv2, sv3));
  m = fmaxf(m, __shfl_xor(m, 1));
  m = fmaxf(m, __shfl_xor(m, 2));
  m = fmaxf(m, __shfl_xor(m, 4));
  float p0 = __expf(sv0 - m), p1 = __expf(sv1 - m), p2 = __expf(sv2 - m);
  float p3 = (jsub < 6) ? __expf(sv3 - m) : 0.f;
  sP[w][h][jsub] = p0;
  sP[w][h][jsub + 8] = p1;
  sP[w][h][jsub + 16] = p2;
  sP[w][h][jsub + 24] = p3;
  float l = p0 + p1 + p2 + p3;
  l += __shfl_xor(l, 1);
  l += __shfl_xor(l, 2);
  l += __shfl_xor(l, 4);

  float o8[8] = {};
  for (int j = 0; j < KNN_K; ++j) {
    int idx = __shfl(myidx, j);
    s16x8 v8 = *(const s16x8*)(qkv + ((size_t)(b * S_LEN + idx)) * QKVD + 2 * DM + lane * 8);
    float p = sP[w][h][j];
#pragma unroll
    for (int i = 0; i < 8; ++i) o8[i] += p * bf2f(v8[i]);
  }
  float inv = 1.f / l;
  s16x8 ov;
#pragma unroll
  for (int i = 0; i < 8; ++i) ov[i] = f2bf(o8[i] * inv);
  *(s16x8*)(o + (size_t)bq * DM + lane * 8) = ov;
}

// ---------------- residual + layernorm (one wave per row of 512) ----------------
__global__ __launch_bounds__(256) void residual_ln(const float* __restrict__ x,
                                                   const float* __restrict__ a,
                                                   const float* __restrict__ g,
                                                   const float* __restrict__ bta,
                                                   float* __restrict__ yf,
                                                   short* __restrict__ yb) {
  int row = blockIdx.x * 4 + (threadIdx.x >> 6);
  int lane = threadIdx.x & 63;
  const float4* xp = (const float4*)(x + (size_t)row * DM);
  const float4* ap = (const float4*)(a + (size_t)row * DM);
  float4 v0 = xp[lane * 2], v1 = xp[lane * 2 + 1];
  float4 a0 = ap[lane * 2], a1 = ap[lane * 2 + 1];
  float r[8] = {v0.x + a0.x, v0.y + a0.y, v0.z + a0.z, v0.w + a0.w,
                v1.x + a1.x, v1.y + a1.y, v1.z + a1.z, v1.w + a1.w};
  float s = 0.f;
#pragma unroll
  for (int j = 0; j < 8; ++j) s += r[j];
  for (int o2 = 32; o2; o2 >>= 1) s += __shfl_xor(s, o2);
  float mean = s * (1.f / DM);
  float vs = 0.f;
#pragma unroll
  for (int j = 0; j < 8; ++j) { float d = r[j] - mean; vs += d * d; }
  for (int o2 = 32; o2; o2 >>= 1) vs += __shfl_xor(vs, o2);
  float inv = rsqrtf(vs * (1.f / DM) + 1e-5f);
  const float4* gp = (const float4*)g;
  const float4* bp = (const float4*)bta;
  float4 g0 = gp[lane * 2], g1 = gp[lane * 2 + 1];
  float4 b0 = bp[lane * 2], b1 = bp[lane * 2 + 1];
  float gg[8] = {g0.x, g0.y, g0.z, g0.w, g1.x, g1.y, g1.z, g1.w};
  float bb[8] = {b0.x, b0.y, b0.z, b0.w, b1.x, b1.y, b1.z, b1.w};
  float y[8];
#pragma unroll
  for (int j = 0; j < 8; ++j) y[j] = (r[j] - mean) * inv * gg[j] + bb[j];
  float4 o0 = {y[0], y[1], y[2], y[3]};
  float4 o1 = {y[4], y[5], y[6], y[7]};
  float4* yp = (float4*)(yf + (size_t)row * DM);
  yp[lane * 2] = o0;
  yp[lane * 2 + 1] = o1;
  if (yb) {
    s16x8 ob;
#pragma unroll
    for (int j = 0; j < 8; ++j) ob[j] = f2bf(y[j]);
    *(s16x8*)(yb + (size_t)row * DM + lane * 8) = ob;
  }
}

// ---------------- launcher ----------------
extern "C" void kernel_launch(void* const* d_in, const int* in_sizes, int n_in,
                              void* d_out, int out_size, void* d_ws, size_t ws_size,
                              hipStream_t stream) {
  const float* x      = (const float*)d_in[0];
  const int*   var    = (const int*)d_in[1];
  const float* times  = (const float*)d_in[2];
  const float* in_w1  = (const float*)d_in[4];
  const float* in_b1  = (const float*)d_in[5];
  const float* out_w1 = (const float*)d_in[6];
  const float* out_b1 = (const float*)d_in[7];
  const float* ln_g1  = (const float*)d_in[8];
  const float* ln_b1  = (const float*)d_in[9];
  const float* in_w2  = (const float*)d_in[10];
  const float* in_b2  = (const float*)d_in[11];
  const float* out_w2 = (const float*)d_in[12];
  const float* out_b2 = (const float*)d_in[13];
  const float* ln_g2  = (const float*)d_in[14];
  const float* ln_b2  = (const float*)d_in[15];
  float* out = (float*)d_out;

  char* ws = (char*)d_ws;
  size_t off = 0;
  auto alloc = [&](size_t bytes) -> char* {
    char* p = ws + off;
    off = (off + bytes + 255) & ~(size_t)255;
    return p;
  };
  short* xb    = (short*)alloc((size_t)NTOK * DM * 2);
  short* x1b   = (short*)alloc((size_t)NTOK * DM * 2);
  short* w1q   = (short*)alloc((size_t)QKVD * DM * 2);
  short* w1o   = (short*)alloc((size_t)DM * DM * 2);
  short* w2q   = (short*)alloc((size_t)QKVD * DM * 2);
  short* w2o   = (short*)alloc((size_t)DM * DM * 2);
  short* qkvb  = (short*)alloc((size_t)NTOK * QKVD * 2);
  short* ob    = (short*)alloc((size_t)NTOK * DM * 2);
  // Overlay region: pqkv (31.5 MB) aliases af+x1f (33.6 MB). Lifetimes are
  // disjoint: pqkv is dead after intra_attn; af/x1f first written after it.
  char*  region = alloc((size_t)NTOK * DM * 4 * 2);          // 33.6 MB
  float* af    = (float*)region;
  float* x1f   = (float*)(region + (size_t)NTOK * DM * 4);
  short* pqkv  = (short*)region;
  int* gcnt    = (int*)alloc((size_t)BATCH * NVAR * 4);
  int* pgoff   = (int*)alloc((size_t)BATCH * NVAR * 4);
  int* porig   = (int*)alloc((size_t)BATCH * PADCAP * 4);
  int* tileV   = (int*)alloc((size_t)BATCH * MAXTILE * 4);
  int* tileQ0  = (int*)alloc((size_t)BATCH * MAXTILE * 4);
  int* ntile   = (int*)alloc((size_t)BATCH * 4);
  int* knn     = (int*)alloc((size_t)NTOK * KNN_K * 4);

  cast_all<<<C_B4 / 256, 256, 0, stream>>>(x, in_w1, out_w1, in_w2, out_w2,
                                           xb, w1q, w1o, w2q, w2o);

  build_groups<<<BATCH, 64, 0, stream>>>(var, gcnt, pgoff, porig, tileV, tileQ0, ntile);
  knn_sel<<<NTOK / 8, 256, 0, stream>>>(var, times, knn);

  // ---- layer 1 (intra-variate dense attention) ----
  gemm_bt<1><<<dim3(QKVD / 128, NTOK / 128), 256, 0, stream>>>(xb, w1q, in_b1, qkvb,
                                                               NTOK, QKVD, DM);
  permute_qkv<<<BATCH * PADCAP, 192, 0, stream>>>(qkvb, porig, pqkv);
  intra_attn<<<dim3(MAXTILE, NH, BATCH), 256, 0, stream>>>(pqkv, porig, tileV, tileQ0,
                                                           ntile, pgoff, gcnt, ob);
  gemm_bt<0><<<dim3(DM / 128, NTOK / 128), 256, 0, stream>>>(ob, w1o, out_b1, af,
                                                             NTOK, DM, DM);
  residual_ln<<<NTOK / 4, 256, 0, stream>>>(x, af, ln_g1, ln_b1, x1f, x1b);

  // ---- layer 2 (inter-variate KNN attention) ----
  gemm_bt<1><<<dim3(QKVD / 128, NTOK / 128), 256, 0, stream>>>(x1b, w2q, in_b2, qkvb,
                                                               NTOK, QKVD, DM);
  inter_attn<<<NTOK / 4, 256, 0, stream>>>(qkvb, knn, ob);
  gemm_bt<0><<<dim3(DM / 128, NTOK / 128), 256, 0, stream>>>(ob, w2o, out_b2, af,
                                                             NTOK, DM, DM);
  residual_ln<<<NTOK / 4, 256, 0, stream>>>(x1f, af, ln_g2, ln_b2, out, nullptr);
}

// Round 10
// 226.329 us; speedup vs baseline: 1.1161x; 1.1161x over previous
//
#include <hip/hip_runtime.h>

// CoFormer attention layer, MI355X gfx950.
// B=4, S=2048, D=512, H=8, dh=64, K=30, NVAR=8. valid_mask all-true ->
// layer1: attend iff same variate (dense per-group attention, MFMA flash).
// layer2: attend iff in 30-NN by |dt| among different variates.
// KNN: tau = exact 30th-smallest key via bit-pattern binary search; set =
// {d < tau} U {first (30-cntLess) idx with d == tau} == jax top_k set.
//
// R9 -> R10: (a) REVERT gemm_bt to R8 reg-staged+prefetch form (R9 gload_lds
// version exposed latency, +8 us). (b) Fuse cast+build_groups+knn into ONE
// block-specialized kernel: knn blocks dispatch first, memory-bound cast
// blocks co-reside in spare wave slots -> serial 76 us becomes ~60 us.

#define S_LEN 2048
#define BATCH 4
#define DM    512
#define NH    8
#define DH    64
#define KNN_K 30
#define NVAR  8
#define NTOK  (BATCH * S_LEN)   // 8192
#define QKVD  (3 * DM)          // 1536
#define PADCAP 2560             // 2048 + 8*64 padding headroom per batch
#define MAXTILE 40              // max q-tiles (64 rows) per batch

typedef float f32x4 __attribute__((ext_vector_type(4)));
typedef short s16x8 __attribute__((ext_vector_type(8)));
typedef short s16x4 __attribute__((ext_vector_type(4)));

__device__ __forceinline__ float bf2f(short u) {
  return __uint_as_float(((unsigned)(unsigned short)u) << 16);
}
__device__ __forceinline__ short f2bf(float f) {
  unsigned x = __float_as_uint(f);
  return (short)((x + 0x7fffu + ((x >> 16) & 1u)) >> 16);   // RNE
}

// ---------------- fused prep: knn (blocks 0..1023) + groups (4) + casts ----------------
#define KNNB (NTOK / 8)               // 1024 knn blocks (4 waves x 2 queries)
#define C_N0 (NTOK * DM / 4)          // x       1048576
#define C_N1 (QKVD * DM / 4)          // in_w*    196608
#define C_N2 (DM * DM / 4)            // out_w*    65536
#define C_B1 (C_N0 + C_N1)
#define C_B2 (C_B1 + C_N2)
#define C_B3 (C_B2 + C_N1)
#define C_B4 (C_B3 + C_N2)            // total 1572864 -> 6144 cast blocks
#define PREP_GRID (KNNB + BATCH + C_B4 / 256)

__global__ __launch_bounds__(256) void prep_all(
    const int* __restrict__ variates, const float* __restrict__ times,
    int* __restrict__ knn_out,
    int* __restrict__ gcnt, int* __restrict__ pgoff, int* __restrict__ porig,
    int* __restrict__ tileV, int* __restrict__ tileQ0, int* __restrict__ ntile,
    const float* __restrict__ s0, const float* __restrict__ s1,
    const float* __restrict__ s2, const float* __restrict__ s3,
    const float* __restrict__ s4, short* __restrict__ d0,
    short* __restrict__ d1, short* __restrict__ d2,
    short* __restrict__ d3, short* __restrict__ d4) {
  int blk = blockIdx.x;
  int tid = threadIdx.x;

  if (blk < KNNB) {
    // ---- KNN-30: dual-query wave, binary search on float bits ----
    int w = tid >> 6, lane = tid & 63;
    int bq0 = blk * 8 + w * 2;
    int bq1 = bq0 + 1;
    int b = bq0 >> 11;
    float tq0 = times[bq0], tq1 = times[bq1];
    int vq0 = variates[bq0], vq1 = variates[bq1];
    const float* tb = times + b * S_LEN;
    const int* vb = variates + b * S_LEN;
    int j0 = lane * 32;

    unsigned u0[32], u1[32];
#pragma unroll
    for (int q = 0; q < 8; ++q) {
      float4 t4 = *(const float4*)(tb + j0 + q * 4);
      int4 v4 = *(const int4*)(vb + j0 + q * 4);
      u0[q * 4 + 0] = __float_as_uint((v4.x == vq0) ? __builtin_inff() : fabsf(tq0 - t4.x));
      u0[q * 4 + 1] = __float_as_uint((v4.y == vq0) ? __builtin_inff() : fabsf(tq0 - t4.y));
      u0[q * 4 + 2] = __float_as_uint((v4.z == vq0) ? __builtin_inff() : fabsf(tq0 - t4.z));
      u0[q * 4 + 3] = __float_as_uint((v4.w == vq0) ? __builtin_inff() : fabsf(tq0 - t4.w));
      u1[q * 4 + 0] = __float_as_uint((v4.x == vq1) ? __builtin_inff() : fabsf(tq1 - t4.x));
      u1[q * 4 + 1] = __float_as_uint((v4.y == vq1) ? __builtin_inff() : fabsf(tq1 - t4.y));
      u1[q * 4 + 2] = __float_as_uint((v4.z == vq1) ? __builtin_inff() : fabsf(tq1 - t4.z));
      u1[q * 4 + 3] = __float_as_uint((v4.w == vq1) ? __builtin_inff() : fabsf(tq1 - t4.w));
    }

    unsigned lo0 = 0u, hi0 = 0x7F800000u;
    unsigned lo1 = 0u, hi1 = 0x7F800000u;
    for (int it = 0; it < 31; ++it) {
      unsigned mid0 = lo0 + ((hi0 - lo0) >> 1);
      unsigned mid1 = lo1 + ((hi1 - lo1) >> 1);
      int c0 = 0, c1 = 0;
#pragma unroll
      for (int k = 0; k < 32; ++k) {
        c0 += (u0[k] <= mid0) ? 1 : 0;
        c1 += (u1[k] <= mid1) ? 1 : 0;
      }
      int pc = c0 | (c1 << 16);        // both counts <= 2048: no carry
#pragma unroll
      for (int o2 = 32; o2; o2 >>= 1) pc += __shfl_xor(pc, o2);
      int pc0 = pc & 0xffff, pc1 = pc >> 16;
      if (lo0 < hi0) { if (pc0 >= KNN_K) hi0 = mid0; else lo0 = mid0 + 1; }
      if (lo1 < hi1) { if (pc1 >= KNN_K) hi1 = mid1; else lo1 = mid1 + 1; }
    }
    unsigned tau0 = lo0, tau1 = lo1;

    int cl0 = 0, ce0 = 0, cl1 = 0, ce1 = 0;
#pragma unroll
    for (int k = 0; k < 32; ++k) {
      cl0 += (u0[k] < tau0) ? 1 : 0;  ce0 += (u0[k] == tau0) ? 1 : 0;
      cl1 += (u1[k] < tau1) ? 1 : 0;  ce1 += (u1[k] == tau1) ? 1 : 0;
    }
    int pa = cl0 | (cl1 << 16), pe = ce0 | (ce1 << 16);
#pragma unroll
    for (int o2 = 1; o2 < 64; o2 <<= 1) {
      int ta = __shfl_up(pa, o2);
      int te = __shfl_up(pe, o2);
      if (lane >= o2) { pa += ta; pe += te; }
    }
    int paTop = __shfl(pa, 63);
    int totL0 = paTop & 0xffff, totL1 = paTop >> 16;
    int excl0 = (pa & 0xffff) - cl0, excl1 = (pa >> 16) - cl1;
    int exce0 = totL0 + (pe & 0xffff) - ce0, exce1 = totL1 + (pe >> 16) - ce1;

    int* op0 = knn_out + bq0 * KNN_K;
    int* op1 = knn_out + bq1 * KNN_K;
    int pos0 = excl0, pos1 = excl1;
#pragma unroll
    for (int k = 0; k < 32; ++k) {
      if (u0[k] < tau0) { op0[pos0] = j0 + k; ++pos0; }
      if (u1[k] < tau1) { op1[pos1] = j0 + k; ++pos1; }
    }
    int r0 = exce0, r1 = exce1;
#pragma unroll
    for (int k = 0; k < 32; ++k) {
      if (u0[k] == tau0) { if (r0 < KNN_K) op0[r0] = j0 + k; ++r0; }
      if (u1[k] == tau1) { if (r1 < KNN_K) op1[r1] = j0 + k; ++r1; }
    }
  } else if (blk < KNNB + BATCH) {
    // ---- group tables (64 active threads; barriers uniform over 256) ----
    int b = blk - KNNB;
    int t = tid;
    __shared__ int scnt[64][NVAR];
    __shared__ int soff[64][NVAR];
    __shared__ int stot[NVAR], sbase[NVAR];
    for (int p = t; p < PADCAP; p += 256) porig[b * PADCAP + p] = -1;
    const int* vb = variates + b * S_LEN;
    int c[NVAR] = {0, 0, 0, 0, 0, 0, 0, 0};
    if (t < 64) {
      for (int j = t * 32; j < t * 32 + 32; ++j) {
        int v = vb[j];
#pragma unroll
        for (int u = 0; u < NVAR; ++u) c[u] += (v == u);
      }
#pragma unroll
      for (int u = 0; u < NVAR; ++u) scnt[t][u] = c[u];
    }
    __syncthreads();
    if (t < NVAR) {
      int a = 0;
      for (int u = 0; u < 64; ++u) { soff[u][t] = a; a += scnt[u][t]; }
      stot[t] = a;
    }
    __syncthreads();
    if (t == 0) {
      int a = 0, nt = 0;
      for (int v = 0; v < NVAR; ++v) {
        sbase[v] = a;
        pgoff[b * NVAR + v] = a;
        gcnt[b * NVAR + v] = stot[v];
        int ntv = (stot[v] + 63) >> 6;
        for (int i = 0; i < ntv; ++i) {
          tileV[b * MAXTILE + nt] = v;
          tileQ0[b * MAXTILE + nt] = a + i * 64;
          ++nt;
        }
        a += ntv * 64;
      }
      ntile[b] = nt;
    }
    __syncthreads();
    if (t < 64) {
      int o[NVAR];
#pragma unroll
      for (int u = 0; u < NVAR; ++u) o[u] = sbase[u] + soff[t][u];
      for (int j = t * 32; j < t * 32 + 32; ++j) {
        int v = vb[j];
        int dst = 0;
#pragma unroll
        for (int u = 0; u < NVAR; ++u) dst += (v == u) ? o[u] : 0;
        porig[b * PADCAP + dst] = j;
#pragma unroll
        for (int u = 0; u < NVAR; ++u) o[u] += (v == u);
      }
    }
  } else {
    // ---- fused casts f32 -> bf16 ----
    int i = (blk - KNNB - BATCH) * 256 + tid;
    const float* src; short* dst; int k;
    if (i < C_N0)      { src = s0; dst = d0; k = i; }
    else if (i < C_B1) { src = s1; dst = d1; k = i - C_N0; }
    else if (i < C_B2) { src = s2; dst = d2; k = i - C_B1; }
    else if (i < C_B3) { src = s3; dst = d3; k = i - C_B2; }
    else               { src = s4; dst = d4; k = i - C_B3; }
    float4 v = ((const float4*)src)[k];
    s16x4 o;
    o[0] = f2bf(v.x); o[1] = f2bf(v.y); o[2] = f2bf(v.z); o[3] = f2bf(v.w);
    ((s16x4*)dst)[k] = o;
  }
}

// ---------------- bf16 MFMA GEMM: C[M,N] = A[M,K] @ B[N,K]^T (+bias) ----------------
// R8 form: reg-staged LDS with cross-barrier prefetch, stride-40 pad.
template <int OUT_BF16>
__global__ __launch_bounds__(256) void gemm_bt(const short* __restrict__ A,
                                               const short* __restrict__ Bm,
                                               const float* __restrict__ bias,
                                               void* __restrict__ Cout,
                                               int M, int N, int K) {
  __shared__ short sA[128 * 40];
  __shared__ short sB[128 * 40];
  int n0 = blockIdx.x * 128, m0 = blockIdx.y * 128;
  int tid = threadIdx.x;
  int lane = tid & 63, wv = tid >> 6;
  int wr = wv >> 1, wc = wv & 1;

  int srow = tid >> 2;
  int scol = (tid & 3) * 8;
  const short* aG = A + (size_t)(m0 + srow) * K + scol;
  const short* bG = Bm + (size_t)(n0 + srow) * K + scol;

  f32x4 acc[4][4] = {};
  int nk = K >> 5;

  s16x8 pa0 = *(const s16x8*)(aG);
  s16x8 pa1 = *(const s16x8*)(aG + (size_t)64 * K);
  s16x8 pb0 = *(const s16x8*)(bG);
  s16x8 pb1 = *(const s16x8*)(bG + (size_t)64 * K);

  for (int kt = 0; kt < nk; ++kt) {
    __syncthreads();
    *(s16x8*)&sA[srow * 40 + scol] = pa0;
    *(s16x8*)&sA[(srow + 64) * 40 + scol] = pa1;
    *(s16x8*)&sB[srow * 40 + scol] = pb0;
    *(s16x8*)&sB[(srow + 64) * 40 + scol] = pb1;
    __syncthreads();
    if (kt + 1 < nk) {
      const short* a2 = aG + (kt + 1) * 32;
      const short* b2 = bG + (kt + 1) * 32;
      pa0 = *(const s16x8*)(a2);
      pa1 = *(const s16x8*)(a2 + (size_t)64 * K);
      pb0 = *(const s16x8*)(b2);
      pb1 = *(const s16x8*)(b2 + (size_t)64 * K);
    }
    int kb = (lane >> 4) * 8;
    int ar = wr * 64 + (lane & 15);
    int br = wc * 64 + (lane & 15);
    s16x8 af[4], bf[4];
#pragma unroll
    for (int m = 0; m < 4; ++m) af[m] = *(const s16x8*)&sA[(ar + m * 16) * 40 + kb];
#pragma unroll
    for (int n = 0; n < 4; ++n) bf[n] = *(const s16x8*)&sB[(br + n * 16) * 40 + kb];
#pragma unroll
    for (int m = 0; m < 4; ++m)
#pragma unroll
      for (int n = 0; n < 4; ++n)
        acc[m][n] = __builtin_amdgcn_mfma_f32_16x16x32_bf16(af[m], bf[n], acc[m][n], 0, 0, 0);
  }

  int crow0 = m0 + wr * 64 + ((lane >> 4) * 4);
  int ccol0 = n0 + wc * 64 + (lane & 15);
#pragma unroll
  for (int n = 0; n < 4; ++n) {
    int col = ccol0 + n * 16;
    float bv = bias ? bias[col] : 0.f;
#pragma unroll
    for (int m = 0; m < 4; ++m) {
#pragma unroll
      for (int j = 0; j < 4; ++j) {
        int row = crow0 + m * 16 + j;
        float val = acc[m][n][j] + bv;
        if (OUT_BF16)
          ((short*)Cout)[(size_t)row * N + col] = f2bf(val);
        else
          ((float*)Cout)[(size_t)row * N + col] = val;
      }
    }
  }
}

// ---------------- permute QKV to group-padded order; zero pads; pre-scale Q ----------------
__global__ __launch_bounds__(192) void permute_qkv(const short* __restrict__ qkvb,
                                                   const int* __restrict__ porig,
                                                   short* __restrict__ pq) {
  int row = blockIdx.x;              // b*PADCAP + p
  int b = row / PADCAP;
  int orig = porig[row];
  int t = threadIdx.x;               // 0..191, 8 shorts each
  s16x8 val;
  if (orig >= 0) {
    val = *(const s16x8*)(qkvb + ((size_t)(b * S_LEN + orig)) * QKVD + t * 8);
    if (t < 64) {                    // Q slice: pre-scale by 1/8 (exact)
#pragma unroll
      for (int i = 0; i < 8; ++i) val[i] = f2bf(bf2f(val[i]) * 0.125f);
    }
  } else {
#pragma unroll
    for (int i = 0; i < 8; ++i) val[i] = 0;
  }
  *(s16x8*)(pq + (size_t)row * QKVD + t * 8) = val;
}

// ---------------- intra attention: dense per-group MFMA flash ----------------
__global__ __launch_bounds__(256) void intra_attn(
    const short* __restrict__ pq, const int* __restrict__ porig,
    const int* __restrict__ tileV, const int* __restrict__ tileQ0,
    const int* __restrict__ ntile, const int* __restrict__ pgoff,
    const int* __restrict__ gcnt, short* __restrict__ o) {
  int b = blockIdx.z, h = blockIdx.y, t = blockIdx.x;
  if (t >= ntile[b]) return;
  int v = tileV[b * MAXTILE + t];
  int q0 = tileQ0[b * MAXTILE + t];
  int k0 = pgoff[b * NVAR + v];
  int L = gcnt[b * NVAR + v];
  int nch = (L + 63) >> 6;

  __shared__ short sQ[2][64][40];
  __shared__ short sK[2][64][40];
  __shared__ short sVT[2][64][40];
  __shared__ short sP[2][64][40];

  int tid = threadIdx.x, lane = tid & 63, w = tid >> 6;
  int colbase = lane & 15;
  int kfrag = (lane >> 4) * 8;

  {
    int r = tid >> 2, cc = (tid & 3) * 16;
    const short* src = pq + ((size_t)(b * PADCAP + q0 + r)) * QKVD + h * DH + cc;
    s16x8 v0 = *(const s16x8*)src;
    s16x8 v1 = *(const s16x8*)(src + 8);
    int half = cc >> 5, kk = cc & 31;
    *(s16x8*)&sQ[half][r][kk] = v0;
    *(s16x8*)&sQ[half][r][kk + 8] = v1;
  }

  f32x4 accO[4] = {};
  float mrun[4], lrun[4];
#pragma unroll
  for (int j = 0; j < 4; ++j) { mrun[j] = -__builtin_inff(); lrun[j] = 0.f; }

  for (int c = 0; c < nch; ++c) {
    __syncthreads();
    {
      int r = tid >> 2, cc = (tid & 3) * 16;
      size_t rowg = (size_t)(b * PADCAP + k0 + c * 64 + r) * QKVD;
      const short* srcK = pq + rowg + DM + h * DH + cc;
      s16x8 k0v = *(const s16x8*)srcK;
      s16x8 k1v = *(const s16x8*)(srcK + 8);
      int half = cc >> 5, kk = cc & 31;
      *(s16x8*)&sK[half][r][kk] = k0v;
      *(s16x8*)&sK[half][r][kk + 8] = k1v;
      const short* srcV = pq + rowg + 2 * DM + h * DH + cc;
      s16x8 v0v = *(const s16x8*)srcV;
      s16x8 v1v = *(const s16x8*)(srcV + 8);
      int khalf = r >> 5, kkv = r & 31;
#pragma unroll
      for (int i = 0; i < 8; ++i) sVT[khalf][cc + i][kkv] = v0v[i];
#pragma unroll
      for (int i = 0; i < 8; ++i) sVT[khalf][cc + 8 + i][kkv] = v1v[i];
    }
    __syncthreads();

    s16x8 aQ0 = *(const s16x8*)&sQ[0][w * 16 + colbase][kfrag];
    s16x8 aQ1 = *(const s16x8*)&sQ[1][w * 16 + colbase][kfrag];
    f32x4 accS[4] = {};
#pragma unroll
    for (int n = 0; n < 4; ++n) {
      s16x8 b0 = *(const s16x8*)&sK[0][n * 16 + colbase][kfrag];
      s16x8 b1 = *(const s16x8*)&sK[1][n * 16 + colbase][kfrag];
      accS[n] = __builtin_amdgcn_mfma_f32_16x16x32_bf16(aQ0, b0, accS[n], 0, 0, 0);
      accS[n] = __builtin_amdgcn_mfma_f32_16x16x32_bf16(aQ1, b1, accS[n], 0, 0, 0);
    }

    float pv[4][4];
#pragma unroll
    for (int j = 0; j < 4; ++j) {
      float cm = -__builtin_inff();
#pragma unroll
      for (int n = 0; n < 4; ++n) {
        bool ok = (c * 64 + n * 16 + colbase) < L;
        float se = ok ? accS[n][j] : -__builtin_inff();
        cm = fmaxf(cm, se);
      }
      for (int o2 = 8; o2; o2 >>= 1) cm = fmaxf(cm, __shfl_xor(cm, o2));
      float mn = fmaxf(mrun[j], cm);
      float al = __expf(mrun[j] - mn);
      float rs = 0.f;
#pragma unroll
      for (int n = 0; n < 4; ++n) {
        bool ok = (c * 64 + n * 16 + colbase) < L;
        float p = ok ? __expf(accS[n][j] - mn) : 0.f;
        pv[n][j] = p;
        rs += p;
      }
      for (int o2 = 8; o2; o2 >>= 1) rs += __shfl_xor(rs, o2);
      lrun[j] = lrun[j] * al + rs;
      mrun[j] = mn;
#pragma unroll
      for (int n = 0; n < 4; ++n) accO[n][j] *= al;
    }

    int prow = w * 16 + ((lane >> 4) << 2);
#pragma unroll
    for (int n = 0; n < 4; ++n)
#pragma unroll
      for (int j = 0; j < 4; ++j)
        sP[n >> 1][prow + j][colbase + ((n & 1) << 4)] = f2bf(pv[n][j]);

    s16x8 aP0 = *(const s16x8*)&sP[0][w * 16 + colbase][kfrag];
    s16x8 aP1 = *(const s16x8*)&sP[1][w * 16 + colbase][kfrag];
#pragma unroll
    for (int n = 0; n < 4; ++n) {
      s16x8 b0 = *(const s16x8*)&sVT[0][n * 16 + colbase][kfrag];
      s16x8 b1 = *(const s16x8*)&sVT[1][n * 16 + colbase][kfrag];
      accO[n] = __builtin_amdgcn_mfma_f32_16x16x32_bf16(aP0, b0, accO[n], 0, 0, 0);
      accO[n] = __builtin_amdgcn_mfma_f32_16x16x32_bf16(aP1, b1, accO[n], 0, 0, 0);
    }
  }

#pragma unroll
  for (int j = 0; j < 4; ++j) {
    int prow = w * 16 + (lane >> 4) * 4 + j;
    int orig = porig[b * PADCAP + q0 + prow];
    if (orig >= 0) {
      float inv = 1.f / lrun[j];
      size_t base = ((size_t)(b * S_LEN + orig)) * DM + h * DH;
#pragma unroll
      for (int n = 0; n < 4; ++n)
        o[base + n * 16 + colbase] = f2bf(accO[n][j] * inv);
    }
  }
}

// ---------------- inter (KNN) attention: one wave per query, all 8 heads ----------------
__global__ __launch_bounds__(256) void inter_attn(const short* __restrict__ qkv,
                                                  const int* __restrict__ knn,
                                                  short* __restrict__ o) {
  __shared__ float sS[4][NH][32];
  __shared__ float sP[4][NH][32];
  int tid = threadIdx.x, lane = tid & 63, w = tid >> 6;
  int bq = blockIdx.x * 4 + w;
  int b = bq >> 11;
  int h = lane >> 3;

  int myidx = (lane < KNN_K) ? knn[bq * KNN_K + lane] : 0;

  s16x8 q8 = *(const s16x8*)(qkv + (size_t)bq * QKVD + lane * 8);
  float qf[8];
#pragma unroll
  for (int i = 0; i < 8; ++i) qf[i] = bf2f(q8[i]) * 0.125f;

  for (int j = 0; j < KNN_K; ++j) {
    int idx = __shfl(myidx, j);
    s16x8 k8 = *(const s16x8*)(qkv + ((size_t)(b * S_LEN + idx)) * QKVD + DM + lane * 8);
    float acc = 0.f;
#pragma unroll
    for (int i = 0; i < 8; ++i) acc += qf[i] * bf2f(k8[i]);
    acc += __shfl_xor(acc, 1);
    acc += __shfl_xor(acc, 2);
    acc += __shfl_xor(acc, 4);
    if ((lane & 7) == 0) sS[w][h][j] = acc;
  }

  int jsub = lane & 7;
  float sv0 = sS[w][h][jsub];
  float sv1 = sS[w][h][jsub + 8];
  float sv2 = sS[w][h][jsub + 16];
  float sv3 = (jsub < 6) ? sS[w][h][jsub + 24] : -__builtin_inff();
  float m = fmaxf(fmaxf(sv0, sv1), fmaxf(sv2, sv3));
  m = fmaxf(m, __shfl_xor(m, 1));
  m = fmaxf(m, __shfl_xor(m, 2));
  m = fmaxf(m, __shfl_xor(m, 4));
  float p0 = __expf(sv0 - m), p1 = __expf(sv1 - m), p2 = __expf(sv2 - m);
  float p3 = (jsub < 6) ? __expf(sv3 - m) : 0.f;
  sP[w][h][jsub] = p0;
  sP[w][h][jsub + 8] = p1;
  sP[w][h][jsub + 16] = p2;
  sP[w][h][jsub + 24] = p3;
  float l = p0 + p1 + p2 + p3;
  l += __shfl_xor(l, 1);
  l += __shfl_xor(l, 2);
  l += __shfl_xor(l, 4);

  float o8[8] = {};
  for (int j = 0; j < KNN_K; ++j) {
    int idx = __shfl(myidx, j);
    s16x8 v8 = *(const s16x8*)(qkv + ((size_t)(b * S_LEN + idx)) * QKVD + 2 * DM + lane * 8);
    float p = sP[w][h][j];
#pragma unroll
    for (int i = 0; i < 8; ++i) o8[i] += p * bf2f(v8[i]);
  }
  float inv = 1.f / l;
  s16x8 ov;
#pragma unroll
  for (int i = 0; i < 8; ++i) ov[i] = f2bf(o8[i] * inv);
  *(s16x8*)(o + (size_t)bq * DM + lane * 8) = ov;
}

// ---------------- residual + layernorm (one wave per row of 512) ----------------
__global__ __launch_bounds__(256) void residual_ln(const float* __restrict__ x,
                                                   const float* __restrict__ a,
                                                   const float* __restrict__ g,
                                                   const float* __restrict__ bta,
                                                   float* __restrict__ yf,
                                                   short* __restrict__ yb) {
  int row = blockIdx.x * 4 + (threadIdx.x >> 6);
  int lane = threadIdx.x & 63;
  const float4* xp = (const float4*)(x + (size_t)row * DM);
  const float4* ap = (const float4*)(a + (size_t)row * DM);
  float4 v0 = xp[lane * 2], v1 = xp[lane * 2 + 1];
  float4 a0 = ap[lane * 2], a1 = ap[lane * 2 + 1];
  float r[8] = {v0.x + a0.x, v0.y + a0.y, v0.z + a0.z, v0.w + a0.w,
                v1.x + a1.x, v1.y + a1.y, v1.z + a1.z, v1.w + a1.w};
  float s = 0.f;
#pragma unroll
  for (int j = 0; j < 8; ++j) s += r[j];
  for (int o2 = 32; o2; o2 >>= 1) s += __shfl_xor(s, o2);
  float mean = s * (1.f / DM);
  float vs = 0.f;
#pragma unroll
  for (int j = 0; j < 8; ++j) { float d = r[j] - mean; vs += d * d; }
  for (int o2 = 32; o2; o2 >>= 1) vs += __shfl_xor(vs, o2);
  float inv = rsqrtf(vs * (1.f / DM) + 1e-5f);
  const float4* gp = (const float4*)g;
  const float4* bp = (const float4*)bta;
  float4 g0 = gp[lane * 2], g1 = gp[lane * 2 + 1];
  float4 b0 = bp[lane * 2], b1 = bp[lane * 2 + 1];
  float gg[8] = {g0.x, g0.y, g0.z, g0.w, g1.x, g1.y, g1.z, g1.w};
  float bb[8] = {b0.x, b0.y, b0.z, b0.w, b1.x, b1.y, b1.z, b1.w};
  float y[8];
#pragma unroll
  for (int j = 0; j < 8; ++j) y[j] = (r[j] - mean) * inv * gg[j] + bb[j];
  float4 o0 = {y[0], y[1], y[2], y[3]};
  float4 o1 = {y[4], y[5], y[6], y[7]};
  float4* yp = (float4*)(yf + (size_t)row * DM);
  yp[lane * 2] = o0;
  yp[lane * 2 + 1] = o1;
  if (yb) {
    s16x8 ob;
#pragma unroll
    for (int j = 0; j < 8; ++j) ob[j] = f2bf(y[j]);
    *(s16x8*)(yb + (size_t)row * DM + lane * 8) = ob;
  }
}

// ---------------- launcher ----------------
extern "C" void kernel_launch(void* const* d_in, const int* in_sizes, int n_in,
                              void* d_out, int out_size, void* d_ws, size_t ws_size,
                              hipStream_t stream) {
  const float* x      = (const float*)d_in[0];
  const int*   var    = (const int*)d_in[1];
  const float* times  = (const float*)d_in[2];
  const float* in_w1  = (const float*)d_in[4];
  const float* in_b1  = (const float*)d_in[5];
  const float* out_w1 = (const float*)d_in[6];
  const float* out_b1 = (const float*)d_in[7];
  const float* ln_g1  = (const float*)d_in[8];
  const float* ln_b1  = (const float*)d_in[9];
  const float* in_w2  = (const float*)d_in[10];
  const float* in_b2  = (const float*)d_in[11];
  const float* out_w2 = (const float*)d_in[12];
  const float* out_b2 = (const float*)d_in[13];
  const float* ln_g2  = (const float*)d_in[14];
  const float* ln_b2  = (const float*)d_in[15];
  float* out = (float*)d_out;

  char* ws = (char*)d_ws;
  size_t off = 0;
  auto alloc = [&](size_t bytes) -> char* {
    char* p = ws + off;
    off = (off + bytes + 255) & ~(size_t)255;
    return p;
  };
  short* xb    = (short*)alloc((size_t)NTOK * DM * 2);
  short* x1b   = (short*)alloc((size_t)NTOK * DM * 2);
  short* w1q   = (short*)alloc((size_t)QKVD * DM * 2);
  short* w1o   = (short*)alloc((size_t)DM * DM * 2);
  short* w2q   = (short*)alloc((size_t)QKVD * DM * 2);
  short* w2o   = (short*)alloc((size_t)DM * DM * 2);
  short* qkvb  = (short*)alloc((size_t)NTOK * QKVD * 2);
  short* ob    = (short*)alloc((size_t)NTOK * DM * 2);
  // Overlay region: pqkv (31.5 MB) aliases af+x1f (33.6 MB). Lifetimes are
  // disjoint: pqkv is dead after intra_attn; af/x1f first written after it.
  char*  region = alloc((size_t)NTOK * DM * 4 * 2);          // 33.6 MB
  float* af    = (float*)region;
  float* x1f   = (float*)(region + (size_t)NTOK * DM * 4);
  short* pqkv  = (short*)region;
  int* gcnt    = (int*)alloc((size_t)BATCH * NVAR * 4);
  int* pgoff   = (int*)alloc((size_t)BATCH * NVAR * 4);
  int* porig   = (int*)alloc((size_t)BATCH * PADCAP * 4);
  int* tileV   = (int*)alloc((size_t)BATCH * MAXTILE * 4);
  int* tileQ0  = (int*)alloc((size_t)BATCH * MAXTILE * 4);
  int* ntile   = (int*)alloc((size_t)BATCH * 4);
  int* knn     = (int*)alloc((size_t)NTOK * KNN_K * 4);

  // fused prep: knn blocks first (long, VALU-bound), cast blocks backfill
  // spare wave slots (memory-bound) and overlap.
  prep_all<<<PREP_GRID, 256, 0, stream>>>(
      var, times, knn, gcnt, pgoff, porig, tileV, tileQ0, ntile,
      x, in_w1, out_w1, in_w2, out_w2, xb, w1q, w1o, w2q, w2o);

  // ---- layer 1 (intra-variate dense attention) ----
  gemm_bt<1><<<dim3(QKVD / 128, NTOK / 128), 256, 0, stream>>>(xb, w1q, in_b1, qkvb,
                                                               NTOK, QKVD, DM);
  permute_qkv<<<BATCH * PADCAP, 192, 0, stream>>>(qkvb, porig, pqkv);
  intra_attn<<<dim3(MAXTILE, NH, BATCH), 256, 0, stream>>>(pqkv, porig, tileV, tileQ0,
                                                           ntile, pgoff, gcnt, ob);
  gemm_bt<0><<<dim3(DM / 128, NTOK / 128), 256, 0, stream>>>(ob, w1o, out_b1, af,
                                                             NTOK, DM, DM);
  residual_ln<<<NTOK / 4, 256, 0, stream>>>(x, af, ln_g1, ln_b1, x1f, x1b);

  // ---- layer 2 (inter-variate KNN attention) ----
  gemm_bt<1><<<dim3(QKVD / 128, NTOK / 128), 256, 0, stream>>>(x1b, w2q, in_b2, qkvb,
                                                               NTOK, QKVD, DM);
  inter_attn<<<NTOK / 4, 256, 0, stream>>>(qkvb, knn, ob);
  gemm_bt<0><<<dim3(DM / 128, NTOK / 128), 256, 0, stream>>>(ob, w2o, out_b2, af,
                                                             NTOK, DM, DM);
  residual_ln<<<NTOK / 4, 256, 0, stream>>>(x1f, af, ln_g2, ln_b2, out, nullptr);
}

// Round 11
// 220.836 us; speedup vs baseline: 1.1438x; 1.0249x over previous
//
#include <hip/hip_runtime.h>

// CoFormer attention layer, MI355X gfx950.
// B=4, S=2048, D=512, H=8, dh=64, K=30, NVAR=8. valid_mask all-true ->
// layer1: attend iff same variate (dense per-group attention, MFMA flash).
// layer2: attend iff in 30-NN by |dt| among different variates.
// KNN: tau = exact 30th-smallest key via bit-pattern binary search; set =
// {d < tau} U {first (30-cntLess) idx with d == tau} == jax top_k set.
//
// R10 -> R11: permute_qkv ELIMINATED. intra_attn stages K/V/Q directly from
// qkvb via porig row indirection (pads clamp to token 0; finite, masked).
// Q-scale 1/8 moved to fp32 post-MFMA (exact). knn search gets uniform
// early-exit. gemm_bt unchanged (R8 reg-staged+prefetch form).

#define S_LEN 2048
#define BATCH 4
#define DM    512
#define NH    8
#define DH    64
#define KNN_K 30
#define NVAR  8
#define NTOK  (BATCH * S_LEN)   // 8192
#define QKVD  (3 * DM)          // 1536
#define PADCAP 2560             // 2048 + 8*64 padding headroom per batch
#define MAXTILE 40              // max q-tiles (64 rows) per batch

typedef float f32x4 __attribute__((ext_vector_type(4)));
typedef short s16x8 __attribute__((ext_vector_type(8)));
typedef short s16x4 __attribute__((ext_vector_type(4)));

__device__ __forceinline__ float bf2f(short u) {
  return __uint_as_float(((unsigned)(unsigned short)u) << 16);
}
__device__ __forceinline__ short f2bf(float f) {
  unsigned x = __float_as_uint(f);
  return (short)((x + 0x7fffu + ((x >> 16) & 1u)) >> 16);   // RNE
}

// ---------------- fused prep: knn (blocks 0..1023) + groups (4) + casts ----------------
#define KNNB (NTOK / 8)               // 1024 knn blocks (4 waves x 2 queries)
#define C_N0 (NTOK * DM / 4)          // x       1048576
#define C_N1 (QKVD * DM / 4)          // in_w*    196608
#define C_N2 (DM * DM / 4)            // out_w*    65536
#define C_B1 (C_N0 + C_N1)
#define C_B2 (C_B1 + C_N2)
#define C_B3 (C_B2 + C_N1)
#define C_B4 (C_B3 + C_N2)            // total 1572864 -> 6144 cast blocks
#define PREP_GRID (KNNB + BATCH + C_B4 / 256)

__global__ __launch_bounds__(256) void prep_all(
    const int* __restrict__ variates, const float* __restrict__ times,
    int* __restrict__ knn_out,
    int* __restrict__ gcnt, int* __restrict__ pgoff, int* __restrict__ porig,
    int* __restrict__ tileV, int* __restrict__ tileQ0, int* __restrict__ ntile,
    const float* __restrict__ s0, const float* __restrict__ s1,
    const float* __restrict__ s2, const float* __restrict__ s3,
    const float* __restrict__ s4, short* __restrict__ d0,
    short* __restrict__ d1, short* __restrict__ d2,
    short* __restrict__ d3, short* __restrict__ d4) {
  int blk = blockIdx.x;
  int tid = threadIdx.x;

  if (blk < KNNB) {
    // ---- KNN-30: dual-query wave, binary search on float bits ----
    int w = tid >> 6, lane = tid & 63;
    int bq0 = blk * 8 + w * 2;
    int bq1 = bq0 + 1;
    int b = bq0 >> 11;
    float tq0 = times[bq0], tq1 = times[bq1];
    int vq0 = variates[bq0], vq1 = variates[bq1];
    const float* tb = times + b * S_LEN;
    const int* vb = variates + b * S_LEN;
    int j0 = lane * 32;

    unsigned u0[32], u1[32];
#pragma unroll
    for (int q = 0; q < 8; ++q) {
      float4 t4 = *(const float4*)(tb + j0 + q * 4);
      int4 v4 = *(const int4*)(vb + j0 + q * 4);
      u0[q * 4 + 0] = __float_as_uint((v4.x == vq0) ? __builtin_inff() : fabsf(tq0 - t4.x));
      u0[q * 4 + 1] = __float_as_uint((v4.y == vq0) ? __builtin_inff() : fabsf(tq0 - t4.y));
      u0[q * 4 + 2] = __float_as_uint((v4.z == vq0) ? __builtin_inff() : fabsf(tq0 - t4.z));
      u0[q * 4 + 3] = __float_as_uint((v4.w == vq0) ? __builtin_inff() : fabsf(tq0 - t4.w));
      u1[q * 4 + 0] = __float_as_uint((v4.x == vq1) ? __builtin_inff() : fabsf(tq1 - t4.x));
      u1[q * 4 + 1] = __float_as_uint((v4.y == vq1) ? __builtin_inff() : fabsf(tq1 - t4.y));
      u1[q * 4 + 2] = __float_as_uint((v4.z == vq1) ? __builtin_inff() : fabsf(tq1 - t4.z));
      u1[q * 4 + 3] = __float_as_uint((v4.w == vq1) ? __builtin_inff() : fabsf(tq1 - t4.w));
    }

    unsigned lo0 = 0u, hi0 = 0x7F800000u;
    unsigned lo1 = 0u, hi1 = 0x7F800000u;
    for (int it = 0; it < 31; ++it) {
      unsigned mid0 = lo0 + ((hi0 - lo0) >> 1);
      unsigned mid1 = lo1 + ((hi1 - lo1) >> 1);
      int c0 = 0, c1 = 0;
#pragma unroll
      for (int k = 0; k < 32; ++k) {
        c0 += (u0[k] <= mid0) ? 1 : 0;
        c1 += (u1[k] <= mid1) ? 1 : 0;
      }
      int pc = c0 | (c1 << 16);        // both counts <= 2048: no carry
#pragma unroll
      for (int o2 = 32; o2; o2 >>= 1) pc += __shfl_xor(pc, o2);
      int pc0 = pc & 0xffff, pc1 = pc >> 16;
      if (lo0 < hi0) { if (pc0 >= KNN_K) hi0 = mid0; else lo0 = mid0 + 1; }
      if (lo1 < hi1) { if (pc1 >= KNN_K) hi1 = mid1; else lo1 = mid1 + 1; }
      if (lo0 >= hi0 && lo1 >= hi1) break;   // wave-uniform
    }
    unsigned tau0 = lo0, tau1 = lo1;

    int cl0 = 0, ce0 = 0, cl1 = 0, ce1 = 0;
#pragma unroll
    for (int k = 0; k < 32; ++k) {
      cl0 += (u0[k] < tau0) ? 1 : 0;  ce0 += (u0[k] == tau0) ? 1 : 0;
      cl1 += (u1[k] < tau1) ? 1 : 0;  ce1 += (u1[k] == tau1) ? 1 : 0;
    }
    int pa = cl0 | (cl1 << 16), pe = ce0 | (ce1 << 16);
#pragma unroll
    for (int o2 = 1; o2 < 64; o2 <<= 1) {
      int ta = __shfl_up(pa, o2);
      int te = __shfl_up(pe, o2);
      if (lane >= o2) { pa += ta; pe += te; }
    }
    int paTop = __shfl(pa, 63);
    int totL0 = paTop & 0xffff, totL1 = paTop >> 16;
    int excl0 = (pa & 0xffff) - cl0, excl1 = (pa >> 16) - cl1;
    int exce0 = totL0 + (pe & 0xffff) - ce0, exce1 = totL1 + (pe >> 16) - ce1;

    int* op0 = knn_out + bq0 * KNN_K;
    int* op1 = knn_out + bq1 * KNN_K;
    int pos0 = excl0, pos1 = excl1;
#pragma unroll
    for (int k = 0; k < 32; ++k) {
      if (u0[k] < tau0) { op0[pos0] = j0 + k; ++pos0; }
      if (u1[k] < tau1) { op1[pos1] = j0 + k; ++pos1; }
    }
    int r0 = exce0, r1 = exce1;
#pragma unroll
    for (int k = 0; k < 32; ++k) {
      if (u0[k] == tau0) { if (r0 < KNN_K) op0[r0] = j0 + k; ++r0; }
      if (u1[k] == tau1) { if (r1 < KNN_K) op1[r1] = j0 + k; ++r1; }
    }
  } else if (blk < KNNB + BATCH) {
    // ---- group tables (64 active threads; barriers uniform over 256) ----
    int b = blk - KNNB;
    int t = tid;
    __shared__ int scnt[64][NVAR];
    __shared__ int soff[64][NVAR];
    __shared__ int stot[NVAR], sbase[NVAR];
    for (int p = t; p < PADCAP; p += 256) porig[b * PADCAP + p] = -1;
    const int* vb = variates + b * S_LEN;
    int c[NVAR] = {0, 0, 0, 0, 0, 0, 0, 0};
    if (t < 64) {
      for (int j = t * 32; j < t * 32 + 32; ++j) {
        int v = vb[j];
#pragma unroll
        for (int u = 0; u < NVAR; ++u) c[u] += (v == u);
      }
#pragma unroll
      for (int u = 0; u < NVAR; ++u) scnt[t][u] = c[u];
    }
    __syncthreads();
    if (t < NVAR) {
      int a = 0;
      for (int u = 0; u < 64; ++u) { soff[u][t] = a; a += scnt[u][t]; }
      stot[t] = a;
    }
    __syncthreads();
    if (t == 0) {
      int a = 0, nt = 0;
      for (int v = 0; v < NVAR; ++v) {
        sbase[v] = a;
        pgoff[b * NVAR + v] = a;
        gcnt[b * NVAR + v] = stot[v];
        int ntv = (stot[v] + 63) >> 6;
        for (int i = 0; i < ntv; ++i) {
          tileV[b * MAXTILE + nt] = v;
          tileQ0[b * MAXTILE + nt] = a + i * 64;
          ++nt;
        }
        a += ntv * 64;
      }
      ntile[b] = nt;
    }
    __syncthreads();
    if (t < 64) {
      int o[NVAR];
#pragma unroll
      for (int u = 0; u < NVAR; ++u) o[u] = sbase[u] + soff[t][u];
      for (int j = t * 32; j < t * 32 + 32; ++j) {
        int v = vb[j];
        int dst = 0;
#pragma unroll
        for (int u = 0; u < NVAR; ++u) dst += (v == u) ? o[u] : 0;
        porig[b * PADCAP + dst] = j;
#pragma unroll
        for (int u = 0; u < NVAR; ++u) o[u] += (v == u);
      }
    }
  } else {
    // ---- fused casts f32 -> bf16 ----
    int i = (blk - KNNB - BATCH) * 256 + tid;
    const float* src; short* dst; int k;
    if (i < C_N0)      { src = s0; dst = d0; k = i; }
    else if (i < C_B1) { src = s1; dst = d1; k = i - C_N0; }
    else if (i < C_B2) { src = s2; dst = d2; k = i - C_B1; }
    else if (i < C_B3) { src = s3; dst = d3; k = i - C_B2; }
    else               { src = s4; dst = d4; k = i - C_B3; }
    float4 v = ((const float4*)src)[k];
    s16x4 o;
    o[0] = f2bf(v.x); o[1] = f2bf(v.y); o[2] = f2bf(v.z); o[3] = f2bf(v.w);
    ((s16x4*)dst)[k] = o;
  }
}

// ---------------- bf16 MFMA GEMM: C[M,N] = A[M,K] @ B[N,K]^T (+bias) ----------------
// R8 form: reg-staged LDS with cross-barrier prefetch, stride-40 pad.
template <int OUT_BF16>
__global__ __launch_bounds__(256) void gemm_bt(const short* __restrict__ A,
                                               const short* __restrict__ Bm,
                                               const float* __restrict__ bias,
                                               void* __restrict__ Cout,
                                               int M, int N, int K) {
  __shared__ short sA[128 * 40];
  __shared__ short sB[128 * 40];
  int n0 = blockIdx.x * 128, m0 = blockIdx.y * 128;
  int tid = threadIdx.x;
  int lane = tid & 63, wv = tid >> 6;
  int wr = wv >> 1, wc = wv & 1;

  int srow = tid >> 2;
  int scol = (tid & 3) * 8;
  const short* aG = A + (size_t)(m0 + srow) * K + scol;
  const short* bG = Bm + (size_t)(n0 + srow) * K + scol;

  f32x4 acc[4][4] = {};
  int nk = K >> 5;

  s16x8 pa0 = *(const s16x8*)(aG);
  s16x8 pa1 = *(const s16x8*)(aG + (size_t)64 * K);
  s16x8 pb0 = *(const s16x8*)(bG);
  s16x8 pb1 = *(const s16x8*)(bG + (size_t)64 * K);

  for (int kt = 0; kt < nk; ++kt) {
    __syncthreads();
    *(s16x8*)&sA[srow * 40 + scol] = pa0;
    *(s16x8*)&sA[(srow + 64) * 40 + scol] = pa1;
    *(s16x8*)&sB[srow * 40 + scol] = pb0;
    *(s16x8*)&sB[(srow + 64) * 40 + scol] = pb1;
    __syncthreads();
    if (kt + 1 < nk) {
      const short* a2 = aG + (kt + 1) * 32;
      const short* b2 = bG + (kt + 1) * 32;
      pa0 = *(const s16x8*)(a2);
      pa1 = *(const s16x8*)(a2 + (size_t)64 * K);
      pb0 = *(const s16x8*)(b2);
      pb1 = *(const s16x8*)(b2 + (size_t)64 * K);
    }
    int kb = (lane >> 4) * 8;
    int ar = wr * 64 + (lane & 15);
    int br = wc * 64 + (lane & 15);
    s16x8 af[4], bf[4];
#pragma unroll
    for (int m = 0; m < 4; ++m) af[m] = *(const s16x8*)&sA[(ar + m * 16) * 40 + kb];
#pragma unroll
    for (int n = 0; n < 4; ++n) bf[n] = *(const s16x8*)&sB[(br + n * 16) * 40 + kb];
#pragma unroll
    for (int m = 0; m < 4; ++m)
#pragma unroll
      for (int n = 0; n < 4; ++n)
        acc[m][n] = __builtin_amdgcn_mfma_f32_16x16x32_bf16(af[m], bf[n], acc[m][n], 0, 0, 0);
  }

  int crow0 = m0 + wr * 64 + ((lane >> 4) * 4);
  int ccol0 = n0 + wc * 64 + (lane & 15);
#pragma unroll
  for (int n = 0; n < 4; ++n) {
    int col = ccol0 + n * 16;
    float bv = bias ? bias[col] : 0.f;
#pragma unroll
    for (int m = 0; m < 4; ++m) {
#pragma unroll
      for (int j = 0; j < 4; ++j) {
        int row = crow0 + m * 16 + j;
        float val = acc[m][n][j] + bv;
        if (OUT_BF16)
          ((short*)Cout)[(size_t)row * N + col] = f2bf(val);
        else
          ((float*)Cout)[(size_t)row * N + col] = val;
      }
    }
  }
}

// ---------------- intra attention: dense per-group MFMA flash ----------------
// Stages rows directly from qkvb via porig indirection (no permuted copy).
// Pads (porig=-1) clamp to token 0: finite data, masked by L in softmax.
__global__ __launch_bounds__(256) void intra_attn(
    const short* __restrict__ qkv, const int* __restrict__ porig,
    const int* __restrict__ tileV, const int* __restrict__ tileQ0,
    const int* __restrict__ ntile, const int* __restrict__ pgoff,
    const int* __restrict__ gcnt, short* __restrict__ o) {
  int b = blockIdx.z, h = blockIdx.y, t = blockIdx.x;
  if (t >= ntile[b]) return;
  int v = tileV[b * MAXTILE + t];
  int q0 = tileQ0[b * MAXTILE + t];
  int k0 = pgoff[b * NVAR + v];
  int L = gcnt[b * NVAR + v];
  int nch = (L + 63) >> 6;

  __shared__ short sQ[2][64][40];
  __shared__ short sK[2][64][40];
  __shared__ short sVT[2][64][40];
  __shared__ short sP[2][64][40];

  int tid = threadIdx.x, lane = tid & 63, w = tid >> 6;
  int colbase = lane & 15;
  int kfrag = (lane >> 4) * 8;

  {
    int r = tid >> 2, cc = (tid & 3) * 16;
    int tok = porig[b * PADCAP + q0 + r];
    if (tok < 0) tok = 0;
    const short* src = qkv + ((size_t)(b * S_LEN + tok)) * QKVD + h * DH + cc;
    s16x8 v0 = *(const s16x8*)src;
    s16x8 v1 = *(const s16x8*)(src + 8);
    int half = cc >> 5, kk = cc & 31;
    *(s16x8*)&sQ[half][r][kk] = v0;
    *(s16x8*)&sQ[half][r][kk + 8] = v1;
  }

  f32x4 accO[4] = {};
  float mrun[4], lrun[4];
#pragma unroll
  for (int j = 0; j < 4; ++j) { mrun[j] = -__builtin_inff(); lrun[j] = 0.f; }

  for (int c = 0; c < nch; ++c) {
    __syncthreads();
    {
      int r = tid >> 2, cc = (tid & 3) * 16;
      int tok = porig[b * PADCAP + k0 + c * 64 + r];
      if (tok < 0) tok = 0;
      size_t rowg = (size_t)(b * S_LEN + tok) * QKVD;
      const short* srcK = qkv + rowg + DM + h * DH + cc;
      s16x8 k0v = *(const s16x8*)srcK;
      s16x8 k1v = *(const s16x8*)(srcK + 8);
      int half = cc >> 5, kk = cc & 31;
      *(s16x8*)&sK[half][r][kk] = k0v;
      *(s16x8*)&sK[half][r][kk + 8] = k1v;
      const short* srcV = qkv + rowg + 2 * DM + h * DH + cc;
      s16x8 v0v = *(const s16x8*)srcV;
      s16x8 v1v = *(const s16x8*)(srcV + 8);
      int khalf = r >> 5, kkv = r & 31;
#pragma unroll
      for (int i = 0; i < 8; ++i) sVT[khalf][cc + i][kkv] = v0v[i];
#pragma unroll
      for (int i = 0; i < 8; ++i) sVT[khalf][cc + 8 + i][kkv] = v1v[i];
    }
    __syncthreads();

    s16x8 aQ0 = *(const s16x8*)&sQ[0][w * 16 + colbase][kfrag];
    s16x8 aQ1 = *(const s16x8*)&sQ[1][w * 16 + colbase][kfrag];
    f32x4 accS[4] = {};
#pragma unroll
    for (int n = 0; n < 4; ++n) {
      s16x8 b0 = *(const s16x8*)&sK[0][n * 16 + colbase][kfrag];
      s16x8 b1 = *(const s16x8*)&sK[1][n * 16 + colbase][kfrag];
      accS[n] = __builtin_amdgcn_mfma_f32_16x16x32_bf16(aQ0, b0, accS[n], 0, 0, 0);
      accS[n] = __builtin_amdgcn_mfma_f32_16x16x32_bf16(aQ1, b1, accS[n], 0, 0, 0);
    }
    // 1/sqrt(dh) scale in fp32 (exact pow2) — replaces bf16 Q pre-scale
#pragma unroll
    for (int n = 0; n < 4; ++n)
#pragma unroll
      for (int j = 0; j < 4; ++j) accS[n][j] *= 0.125f;

    float pv[4][4];
#pragma unroll
    for (int j = 0; j < 4; ++j) {
      float cm = -__builtin_inff();
#pragma unroll
      for (int n = 0; n < 4; ++n) {
        bool ok = (c * 64 + n * 16 + colbase) < L;
        float se = ok ? accS[n][j] : -__builtin_inff();
        cm = fmaxf(cm, se);
      }
      for (int o2 = 8; o2; o2 >>= 1) cm = fmaxf(cm, __shfl_xor(cm, o2));
      float mn = fmaxf(mrun[j], cm);
      float al = __expf(mrun[j] - mn);
      float rs = 0.f;
#pragma unroll
      for (int n = 0; n < 4; ++n) {
        bool ok = (c * 64 + n * 16 + colbase) < L;
        float p = ok ? __expf(accS[n][j] - mn) : 0.f;
        pv[n][j] = p;
        rs += p;
      }
      for (int o2 = 8; o2; o2 >>= 1) rs += __shfl_xor(rs, o2);
      lrun[j] = lrun[j] * al + rs;
      mrun[j] = mn;
#pragma unroll
      for (int n = 0; n < 4; ++n) accO[n][j] *= al;
    }

    int prow = w * 16 + ((lane >> 4) << 2);
#pragma unroll
    for (int n = 0; n < 4; ++n)
#pragma unroll
      for (int j = 0; j < 4; ++j)
        sP[n >> 1][prow + j][colbase + ((n & 1) << 4)] = f2bf(pv[n][j]);

    s16x8 aP0 = *(const s16x8*)&sP[0][w * 16 + colbase][kfrag];
    s16x8 aP1 = *(const s16x8*)&sP[1][w * 16 + colbase][kfrag];
#pragma unroll
    for (int n = 0; n < 4; ++n) {
      s16x8 b0 = *(const s16x8*)&sVT[0][n * 16 + colbase][kfrag];
      s16x8 b1 = *(const s16x8*)&sVT[1][n * 16 + colbase][kfrag];
      accO[n] = __builtin_amdgcn_mfma_f32_16x16x32_bf16(aP0, b0, accO[n], 0, 0, 0);
      accO[n] = __builtin_amdgcn_mfma_f32_16x16x32_bf16(aP1, b1, accO[n], 0, 0, 0);
    }
  }

#pragma unroll
  for (int j = 0; j < 4; ++j) {
    int prow = w * 16 + (lane >> 4) * 4 + j;
    int orig = porig[b * PADCAP + q0 + prow];
    if (orig >= 0) {
      float inv = 1.f / lrun[j];
      size_t base = ((size_t)(b * S_LEN + orig)) * DM + h * DH;
#pragma unroll
      for (int n = 0; n < 4; ++n)
        o[base + n * 16 + colbase] = f2bf(accO[n][j] * inv);
    }
  }
}

// ---------------- inter (KNN) attention: one wave per query, all 8 heads ----------------
__global__ __launch_bounds__(256) void inter_attn(const short* __restrict__ qkv,
                                                  const int* __restrict__ knn,
                                                  short* __restrict__ o) {
  __shared__ float sS[4][NH][32];
  __shared__ float sP[4][NH][32];
  int tid = threadIdx.x, lane = tid & 63, w = tid >> 6;
  int bq = blockIdx.x * 4 + w;
  int b = bq >> 11;
  int h = lane >> 3;

  int myidx = (lane < KNN_K) ? knn[bq * KNN_K + lane] : 0;

  s16x8 q8 = *(const s16x8*)(qkv + (size_t)bq * QKVD + lane * 8);
  float qf[8];
#pragma unroll
  for (int i = 0; i < 8; ++i) qf[i] = bf2f(q8[i]) * 0.125f;

  for (int j = 0; j < KNN_K; ++j) {
    int idx = __shfl(myidx, j);
    s16x8 k8 = *(const s16x8*)(qkv + ((size_t)(b * S_LEN + idx)) * QKVD + DM + lane * 8);
    float acc = 0.f;
#pragma unroll
    for (int i = 0; i < 8; ++i) acc += qf[i] * bf2f(k8[i]);
    acc += __shfl_xor(acc, 1);
    acc += __shfl_xor(acc, 2);
    acc += __shfl_xor(acc, 4);
    if ((lane & 7) == 0) sS[w][h][j] = acc;
  }

  int jsub = lane & 7;
  float sv0 = sS[w][h][jsub];
  float sv1 = sS[w][h][jsub + 8];
  float sv2 = sS[w][h][jsub + 16];
  float sv3 = (jsub < 6) ? sS[w][h][jsub + 24] : -__builtin_inff();
  float m = fmaxf(fmaxf(sv0, sv1), fmaxf(sv2, sv3));
  m = fmaxf(m, __shfl_xor(m, 1));
  m = fmaxf(m, __shfl_xor(m, 2));
  m = fmaxf(m, __shfl_xor(m, 4));
  float p0 = __expf(sv0 - m), p1 = __expf(sv1 - m), p2 = __expf(sv2 - m);
  float p3 = (jsub < 6) ? __expf(sv3 - m) : 0.f;
  sP[w][h][jsub] = p0;
  sP[w][h][jsub + 8] = p1;
  sP[w][h][jsub + 16] = p2;
  sP[w][h][jsub + 24] = p3;
  float l = p0 + p1 + p2 + p3;
  l += __shfl_xor(l, 1);
  l += __shfl_xor(l, 2);
  l += __shfl_xor(l, 4);

  float o8[8] = {};
  for (int j = 0; j < KNN_K; ++j) {
    int idx = __shfl(myidx, j);
    s16x8 v8 = *(const s16x8*)(qkv + ((size_t)(b * S_LEN + idx)) * QKVD + 2 * DM + lane * 8);
    float p = sP[w][h][j];
#pragma unroll
    for (int i = 0; i < 8; ++i) o8[i] += p * bf2f(v8[i]);
  }
  float inv = 1.f / l;
  s16x8 ov;
#pragma unroll
  for (int i = 0; i < 8; ++i) ov[i] = f2bf(o8[i] * inv);
  *(s16x8*)(o + (size_t)bq * DM + lane * 8) = ov;
}

// ---------------- residual + layernorm (one wave per row of 512) ----------------
__global__ __launch_bounds__(256) void residual_ln(const float* __restrict__ x,
                                                   const float* __restrict__ a,
                                                   const float* __restrict__ g,
                                                   const float* __restrict__ bta,
                                                   float* __restrict__ yf,
                                                   short* __restrict__ yb) {
  int row = blockIdx.x * 4 + (threadIdx.x >> 6);
  int lane = threadIdx.x & 63;
  const float4* xp = (const float4*)(x + (size_t)row * DM);
  const float4* ap = (const float4*)(a + (size_t)row * DM);
  float4 v0 = xp[lane * 2], v1 = xp[lane * 2 + 1];
  float4 a0 = ap[lane * 2], a1 = ap[lane * 2 + 1];
  float r[8] = {v0.x + a0.x, v0.y + a0.y, v0.z + a0.z, v0.w + a0.w,
                v1.x + a1.x, v1.y + a1.y, v1.z + a1.z, v1.w + a1.w};
  float s = 0.f;
#pragma unroll
  for (int j = 0; j < 8; ++j) s += r[j];
  for (int o2 = 32; o2; o2 >>= 1) s += __shfl_xor(s, o2);
  float mean = s * (1.f / DM);
  float vs = 0.f;
#pragma unroll
  for (int j = 0; j < 8; ++j) { float d = r[j] - mean; vs += d * d; }
  for (int o2 = 32; o2; o2 >>= 1) vs += __shfl_xor(vs, o2);
  float inv = rsqrtf(vs * (1.f / DM) + 1e-5f);
  const float4* gp = (const float4*)g;
  const float4* bp = (const float4*)bta;
  float4 g0 = gp[lane * 2], g1 = gp[lane * 2 + 1];
  float4 b0 = bp[lane * 2], b1 = bp[lane * 2 + 1];
  float gg[8] = {g0.x, g0.y, g0.z, g0.w, g1.x, g1.y, g1.z, g1.w};
  float bb[8] = {b0.x, b0.y, b0.z, b0.w, b1.x, b1.y, b1.z, b1.w};
  float y[8];
#pragma unroll
  for (int j = 0; j < 8; ++j) y[j] = (r[j] - mean) * inv * gg[j] + bb[j];
  float4 o0 = {y[0], y[1], y[2], y[3]};
  float4 o1 = {y[4], y[5], y[6], y[7]};
  float4* yp = (float4*)(yf + (size_t)row * DM);
  yp[lane * 2] = o0;
  yp[lane * 2 + 1] = o1;
  if (yb) {
    s16x8 ob;
#pragma unroll
    for (int j = 0; j < 8; ++j) ob[j] = f2bf(y[j]);
    *(s16x8*)(yb + (size_t)row * DM + lane * 8) = ob;
  }
}

// ---------------- launcher ----------------
extern "C" void kernel_launch(void* const* d_in, const int* in_sizes, int n_in,
                              void* d_out, int out_size, void* d_ws, size_t ws_size,
                              hipStream_t stream) {
  const float* x      = (const float*)d_in[0];
  const int*   var    = (const int*)d_in[1];
  const float* times  = (const float*)d_in[2];
  const float* in_w1  = (const float*)d_in[4];
  const float* in_b1  = (const float*)d_in[5];
  const float* out_w1 = (const float*)d_in[6];
  const float* out_b1 = (const float*)d_in[7];
  const float* ln_g1  = (const float*)d_in[8];
  const float* ln_b1  = (const float*)d_in[9];
  const float* in_w2  = (const float*)d_in[10];
  const float* in_b2  = (const float*)d_in[11];
  const float* out_w2 = (const float*)d_in[12];
  const float* out_b2 = (const float*)d_in[13];
  const float* ln_g2  = (const float*)d_in[14];
  const float* ln_b2  = (const float*)d_in[15];
  float* out = (float*)d_out;

  char* ws = (char*)d_ws;
  size_t off = 0;
  auto alloc = [&](size_t bytes) -> char* {
    char* p = ws + off;
    off = (off + bytes + 255) & ~(size_t)255;
    return p;
  };
  short* xb    = (short*)alloc((size_t)NTOK * DM * 2);
  short* x1b   = (short*)alloc((size_t)NTOK * DM * 2);
  short* w1q   = (short*)alloc((size_t)QKVD * DM * 2);
  short* w1o   = (short*)alloc((size_t)DM * DM * 2);
  short* w2q   = (short*)alloc((size_t)QKVD * DM * 2);
  short* w2o   = (short*)alloc((size_t)DM * DM * 2);
  short* qkvb  = (short*)alloc((size_t)NTOK * QKVD * 2);
  short* ob    = (short*)alloc((size_t)NTOK * DM * 2);
  float* af    = (float*)alloc((size_t)NTOK * DM * 4);
  float* x1f   = (float*)alloc((size_t)NTOK * DM * 4);
  int* gcnt    = (int*)alloc((size_t)BATCH * NVAR * 4);
  int* pgoff   = (int*)alloc((size_t)BATCH * NVAR * 4);
  int* porig   = (int*)alloc((size_t)BATCH * PADCAP * 4);
  int* tileV   = (int*)alloc((size_t)BATCH * MAXTILE * 4);
  int* tileQ0  = (int*)alloc((size_t)BATCH * MAXTILE * 4);
  int* ntile   = (int*)alloc((size_t)BATCH * 4);
  int* knn     = (int*)alloc((size_t)NTOK * KNN_K * 4);

  // fused prep: knn blocks first (long, VALU-bound), cast blocks backfill
  prep_all<<<PREP_GRID, 256, 0, stream>>>(
      var, times, knn, gcnt, pgoff, porig, tileV, tileQ0, ntile,
      x, in_w1, out_w1, in_w2, out_w2, xb, w1q, w1o, w2q, w2o);

  // ---- layer 1 (intra-variate dense attention) ----
  gemm_bt<1><<<dim3(QKVD / 128, NTOK / 128), 256, 0, stream>>>(xb, w1q, in_b1, qkvb,
                                                               NTOK, QKVD, DM);
  intra_attn<<<dim3(MAXTILE, NH, BATCH), 256, 0, stream>>>(qkvb, porig, tileV, tileQ0,
                                                           ntile, pgoff, gcnt, ob);
  gemm_bt<0><<<dim3(DM / 128, NTOK / 128), 256, 0, stream>>>(ob, w1o, out_b1, af,
                                                             NTOK, DM, DM);
  residual_ln<<<NTOK / 4, 256, 0, stream>>>(x, af, ln_g1, ln_b1, x1f, x1b);

  // ---- layer 2 (inter-variate KNN attention) ----
  gemm_bt<1><<<dim3(QKVD / 128, NTOK / 128), 256, 0, stream>>>(x1b, w2q, in_b2, qkvb,
                                                               NTOK, QKVD, DM);
  inter_attn<<<NTOK / 4, 256, 0, stream>>>(qkvb, knn, ob);
  gemm_bt<0><<<dim3(DM / 128, NTOK / 128), 256, 0, stream>>>(ob, w2o, out_b2, af,
                                                             NTOK, DM, DM);
  residual_ln<<<NTOK / 4, 256, 0, stream>>>(x1f, af, ln_g2, ln_b2, out, nullptr);
}